// Round 18
// baseline (587.466 us; speedup 1.0000x reference)
//
#include <hip/hip_runtime.h>

// LSTM, B=128, T=256 (255 steps), H=512, V=128, C=128.  OUTPUT = FLOAT32.
// 8 groups x 16 batch rows; 32 WGs/group; WG w owns h-cols [16w,16w+16).
// Wave v (of 4) = K-slice ks in [4v,4v+4) for ALL 4 gates.
// Round 18: TAGLESS SELF-VALIDATING EXCHANGE. Each exchanged u64 packs
// [h0_j,h0_j+1 | h1_j,h1_j+1]; the LSBs of the two h1 bf16s carry a 2-bit
// step field F(s)=((s>>2)+1)&3 (error ~2^-16, invisible). Consumer loads
// speculatively (plain, cold-L1 -> fresh from XCD L2), checks bits, and only
// on miss falls back to agent-scope atomic re-sweeps (r9-proven coherent
// path; plain re-loads would hit stale L1 per r12 probe). Producer: one
// plain 8B store -- NO vmcnt drain, NO tag post. All-to-all bit-gating
// keeps group skew <=1 step; 4 parities x 2-bit field safe to 16 steps.
// g_hbuf memset per launch (replay-safe). Fallback capped -> no silent hang.

typedef __attribute__((ext_vector_type(8))) short short8;
typedef __attribute__((ext_vector_type(4))) float f32x4;
typedef __attribute__((ext_vector_type(4))) unsigned int u32x4;

#define NGROUPS 8
#define HDIM 512
#define TT 256
#define NSTEPS 255
#define CDIM 128
#define PGQ 4096          // u64 words per (parity,group)

__device__ unsigned long long g_hbuf[4 * NGROUPS * PGQ];   // 1 MB, 4 parities

static __device__ __forceinline__ unsigned short f32_to_bf16(float f) {
  unsigned int u = __builtin_bit_cast(unsigned int, f);
  u += 0x7fffu + ((u >> 16) & 1u);   // RNE
  return (unsigned short)(u >> 16);
}
static __device__ __forceinline__ float bf16_to_f32(unsigned short s) {
  unsigned int u = ((unsigned int)s) << 16;
  return __builtin_bit_cast(float, u);
}
static __device__ __forceinline__ float fast_sigmoid(float v) {
  return __builtin_amdgcn_rcpf(1.0f + __expf(-v));
}
static __device__ __forceinline__ float fast_tanh(float v) {
  return 1.0f - 2.0f * __builtin_amdgcn_rcpf(1.0f + __expf(2.0f * v));
}
static __device__ __forceinline__ unsigned long long ag_ld64(const unsigned long long* p) {
  return __hip_atomic_load(p, __ATOMIC_RELAXED, __HIP_MEMORY_SCOPE_AGENT);
}
// step-field bits for data of step s, as a mask on the h1-pair word
static __device__ __forceinline__ unsigned int fbits(int s) {
  const unsigned int F = (unsigned int)(((s >> 2) + 1) & 3);
  return (F & 1u) | ((F >> 1) << 16);
}

__global__ __launch_bounds__(256, 1) void lstm_persistent(
    const int* __restrict__ x,
    const float* __restrict__ Wxg, const float* __restrict__ Whg,
    const float* __restrict__ Wxi, const float* __restrict__ Whi,
    const float* __restrict__ Wxf, const float* __restrict__ Whf,
    const float* __restrict__ Wxo, const float* __restrict__ Who,
    const float* __restrict__ Whp,
    const float* __restrict__ bg, const float* __restrict__ bi,
    const float* __restrict__ bf, const float* __restrict__ bo,
    const float* __restrict__ bp,
    float* __restrict__ out)
{
  const int bid = blockIdx.x;
  const int g = bid & 7;
  const int w = bid >> 3;
  const int tid = threadIdx.x;
  const int wave = tid >> 6;
  const int lane = tid & 63;
  const int lane15 = lane & 15;
  const int lanehi = lane >> 4;

  __shared__ __align__(16) float part[2][4][16][16][4]; // [pb][wv][row][col][gate]
  __shared__ int lds_x[16][TT];                         // 16KB

  for (int i = tid; i < 16 * TT; i += 256)
    ((int*)lds_x)[i] = x[g * 16 * TT + i];

  // ---- one-time: W_h fragments, 2-plane bf16 split, this wave's 4 k-steps ----
  const float* Whs[4] = {Whg, Whi, Whf, Who};
  const int bcol = (w << 4) + lane15;
  short8 wf[4][4][2];
#pragma unroll
  for (int gate = 0; gate < 4; ++gate) {
    const float* Wh = Whs[gate];
#pragma unroll
    for (int ksl = 0; ksl < 4; ++ksl) {
      const int ksg = (wave << 2) + ksl;
      short8 s0, s1;
#pragma unroll
      for (int e = 0; e < 8; ++e) {
        float v = Wh[(ksg * 32 + lanehi * 8 + e) * HDIM + bcol];
        unsigned short a = f32_to_bf16(v);
        unsigned short b = f32_to_bf16(v - bf16_to_f32(a));
        s0[e] = (short)a; s1[e] = (short)b;
      }
      wf[gate][ksl][0] = s0; wf[gate][ksl][1] = s1;
    }
  }
  __syncthreads();   // lds_x ready

  // ---- elementwise mapping ----
  const int brow = tid >> 4;
  const int jl = tid & 15;
  const int j = (w << 4) + jl;
  const float bgv = bg[j], biv = bi[j], bfv = bf[j], bov = bo[j];
  const int pidx = ((j >> 5) << 8) + ((((j >> 3) & 3) << 4) + brow) * 4 + ((j & 7) >> 1);

  float creg = 0.0f;

  for (int t = 0; t < NSTEPS; ++t) {
    // x-gather issued early (flies during the data wait)
    const int idx = lds_x[brow][t];
    const float xgv = Wxg[idx * HDIM + j];
    const float xiv = Wxi[idx * HDIM + j];
    const float xfv = Wxf[idx * HDIM + j];
    const float xov = Wxo[idx * HDIM + j];

    f32x4 accA[4] = {{0.f,0.f,0.f,0.f},{0.f,0.f,0.f,0.f},
                     {0.f,0.f,0.f,0.f},{0.f,0.f,0.f,0.f}};
    f32x4 accB[4] = {{0.f,0.f,0.f,0.f},{0.f,0.f,0.f,0.f},
                     {0.f,0.f,0.f,0.f},{0.f,0.f,0.f,0.f}};
    if (t > 0) {
      const unsigned int expw = fbits(t);
      const unsigned long long* p0q =
          g_hbuf + ((size_t)((t & 3) * NGROUPS + g)) * PGQ;
      u32x4 qa[8];   // [ksl*2 + half]: {lo0,hi0,lo1,hi1} of 2 u64s each

      // ---- speculative plain loads (cold L1 -> fresh from XCD L2) ----
#pragma unroll
      for (int ksl = 0; ksl < 4; ++ksl) {
        const int base = ((wave << 2) + ksl) * 256 + (lane << 2);
        qa[ksl * 2]     = *(const u32x4*)(p0q + base);
        qa[ksl * 2 + 1] = *(const u32x4*)(p0q + base + 2);
      }
      int ok = 1;
#pragma unroll
      for (int i = 0; i < 8; ++i)
        ok &= (((qa[i][1] ^ expw) & 0x00010001u) == 0u) &
              (((qa[i][3] ^ expw) & 0x00010001u) == 0u);

      // ---- fallback: agent-scope atomic re-sweep (coherent re-poll) ----
      unsigned int sweeps = 0;
      while (!__all(ok)) {
        __builtin_amdgcn_s_sleep(1);
#pragma unroll
        for (int ksl = 0; ksl < 4; ++ksl) {
          const int base = ((wave << 2) + ksl) * 256 + (lane << 2);
#pragma unroll
          for (int u = 0; u < 2; ++u) {
            const unsigned long long v0 = ag_ld64(p0q + base + 2 * u);
            const unsigned long long v1 = ag_ld64(p0q + base + 2 * u + 1);
            qa[ksl * 2 + u][0] = (unsigned int)v0;
            qa[ksl * 2 + u][1] = (unsigned int)(v0 >> 32);
            qa[ksl * 2 + u][2] = (unsigned int)v1;
            qa[ksl * 2 + u][3] = (unsigned int)(v1 >> 32);
          }
        }
        ok = 1;
#pragma unroll
        for (int i = 0; i < 8; ++i)
          ok &= (((qa[i][1] ^ expw) & 0x00010001u) == 0u) &
                (((qa[i][3] ^ expw) & 0x00010001u) == 0u);
        if (++sweeps > 65536u) break;   // bug -> wrong answer, not hang
      }

      // ---- unpack planes + 8 independent MFMA chains ----
#pragma unroll
      for (int ksl = 0; ksl < 4; ++ksl) {
        const u32x4 A = qa[ksl * 2], B = qa[ksl * 2 + 1];
        const short8 a0 = __builtin_bit_cast(short8, (u32x4){A[0], A[2], B[0], B[2]});
        const short8 a1 = __builtin_bit_cast(short8, (u32x4){A[1], A[3], B[1], B[3]});
        if (ksl < 2) {
#pragma unroll
          for (int gate = 0; gate < 4; ++gate) {
            accA[gate] = __builtin_amdgcn_mfma_f32_16x16x32_bf16(a0, wf[gate][ksl][0], accA[gate], 0, 0, 0);
            accA[gate] = __builtin_amdgcn_mfma_f32_16x16x32_bf16(a0, wf[gate][ksl][1], accA[gate], 0, 0, 0);
            accA[gate] = __builtin_amdgcn_mfma_f32_16x16x32_bf16(a1, wf[gate][ksl][0], accA[gate], 0, 0, 0);
          }
        } else {
#pragma unroll
          for (int gate = 0; gate < 4; ++gate) {
            accB[gate] = __builtin_amdgcn_mfma_f32_16x16x32_bf16(a0, wf[gate][ksl][0], accB[gate], 0, 0, 0);
            accB[gate] = __builtin_amdgcn_mfma_f32_16x16x32_bf16(a0, wf[gate][ksl][1], accB[gate], 0, 0, 0);
            accB[gate] = __builtin_amdgcn_mfma_f32_16x16x32_bf16(a1, wf[gate][ksl][0], accB[gate], 0, 0, 0);
          }
        }
      }
    }

    {
      const int crow = lanehi << 2;   // C/D: row=(lane>>4)*4+r, col=lane&15
      const int pb = t & 1;
#pragma unroll
      for (int r = 0; r < 4; ++r) {
        f32x4 vr;
#pragma unroll
        for (int gate = 0; gate < 4; ++gate)
          vr[gate] = accA[gate][r] + accB[gate][r];
        *(f32x4*)&part[pb][wave][crow + r][lane15][0] = vr;   // ds_write_b128
      }
    }
    __syncthreads();   // the ONE barrier per step

    const int pb = t & 1;
    const f32x4 s0 = *(const f32x4*)&part[pb][0][brow][jl][0];
    const f32x4 s1 = *(const f32x4*)&part[pb][1][brow][jl][0];
    const f32x4 s2 = *(const f32x4*)&part[pb][2][brow][jl][0];
    const f32x4 s3 = *(const f32x4*)&part[pb][3][brow][jl][0];
    const f32x4 pre = s0 + s1 + s2 + s3;
    const float pg = pre[0] + xgv + bgv;
    const float pi = pre[1] + xiv + biv;
    const float pf = pre[2] + xfv + bfv;
    const float po = pre[3] + xov + bov;
    const float gv = fast_tanh(pg);
    const float iv = fast_sigmoid(pi);
    const float fv = fast_sigmoid(pf);
    const float ov = fast_sigmoid(po);
    creg = gv * iv + creg * fv;
    const float hv = fast_tanh(creg) * ov;

    // pack u64 [h0 pair | h1 pair], embed step field in h1 LSBs; plain store
    const unsigned short h0 = f32_to_bf16(hv);
    const unsigned short h1 = f32_to_bf16(hv - bf16_to_f32(h0));
    const unsigned int pa = (unsigned int)h0 | ((unsigned int)h1 << 16);
    const unsigned int na = (unsigned int)__shfl_xor((int)pa, 1);
    if (!(jl & 1)) {
      unsigned long long* dstq =
          g_hbuf + ((size_t)(((t + 1) & 3) * NGROUPS + g)) * PGQ;
      const unsigned int w0 = (pa & 0xffffu) | ((na & 0xffffu) << 16);   // h0 pair
      unsigned int w1 = (pa >> 16) | (na & 0xffff0000u);                 // h1 pair
      w1 = (w1 & ~0x00010001u) | fbits(t + 1);
      dstq[pidx] = (unsigned long long)w0 | ((unsigned long long)w1 << 32);
    }
    // no vmcnt drain, no tag post: the data self-announces via its bits
  }

  // ---- epilogue: out = h^255 @ W_hp + b_p ----
  __syncthreads();
  {
    const unsigned long long* srcq =
        g_hbuf + ((size_t)((NSTEPS & 3) * NGROUPS + g)) * PGQ;
    const int bq = tid >> 4;
    const int q15 = tid & 15;
    const int cloc = q15 >> 2;
    const int ksl2 = q15 & 3;
    const int cc = (w << 2) + cloc;
    const unsigned long long expq =
        (unsigned long long)fbits(NSTEPS) << 32;   // == 0 for s=255
    float sum = 0.0f;
    for (int k = ksl2 * 128; k < ksl2 * 128 + 128; k += 2) {
      const int pk = ((k >> 5) << 8) + ((((k >> 3) & 3) << 4) + bq) * 4 + ((k & 7) >> 1);
      unsigned long long qv = srcq[pk];
      if (((qv >> 32) & 0x00010001ull) != (expq >> 32)) {
        unsigned int tries = 0;
        do {
          __builtin_amdgcn_s_sleep(1);
          qv = ag_ld64(srcq + pk);
        } while (((qv >> 32) & 0x00010001ull) != (expq >> 32) &&
                 ++tries < 65536u);
      }
      const unsigned int w0 = (unsigned int)qv;
      const unsigned int w1 = (unsigned int)(qv >> 32);
      const float hk0 = bf16_to_f32((unsigned short)(w0 & 0xffffu)) +
                        bf16_to_f32((unsigned short)(w1 & 0xffffu));
      const float hk1 = bf16_to_f32((unsigned short)(w0 >> 16)) +
                        bf16_to_f32((unsigned short)(w1 >> 16));
      sum += hk0 * Whp[k * CDIM + cc] + hk1 * Whp[(k + 1) * CDIM + cc];
    }
    float* gb = &part[0][0][0][0][0];
    gb[tid] = sum;
    __syncthreads();
    if (ksl2 == 0) {
      const float res = gb[tid] + gb[tid + 1] + gb[tid + 2] + gb[tid + 3] + bp[cc];
      out[(g * 16 + bq) * CDIM + cc] = res;
    }
  }
}

extern "C" void kernel_launch(void* const* d_in, const int* in_sizes, int n_in,
                              void* d_out, int out_size, void* d_ws, size_t ws_size,
                              hipStream_t stream) {
  (void)in_sizes; (void)n_in; (void)out_size; (void)d_ws; (void)ws_size;
  const int* x = (const int*)d_in[0];
  const float* Wxg = (const float*)d_in[1];
  const float* Whg = (const float*)d_in[2];
  const float* Wxi = (const float*)d_in[3];
  const float* Whi = (const float*)d_in[4];
  const float* Wxf = (const float*)d_in[5];
  const float* Whf = (const float*)d_in[6];
  const float* Wxo = (const float*)d_in[7];
  const float* Who = (const float*)d_in[8];
  const float* Whp = (const float*)d_in[9];
  const float* bg = (const float*)d_in[10];
  const float* bi = (const float*)d_in[11];
  const float* bf = (const float*)d_in[12];
  const float* bo = (const float*)d_in[13];
  const float* bp = (const float*)d_in[14];
  float* out = (float*)d_out;

  // zero the exchange buffer every launch: makes the embedded step-field
  // protocol replay-safe (stale fields from a previous launch never match)
  void* hbuf_dev = nullptr;
  hipGetSymbolAddress(&hbuf_dev, HIP_SYMBOL(g_hbuf));
  hipMemsetAsync(hbuf_dev, 0, sizeof(g_hbuf), stream);

  lstm_persistent<<<dim3(256), dim3(256), 0, stream>>>(
      x, Wxg, Whg, Wxi, Whi, Wxf, Whf, Wxo, Who, Whp,
      bg, bi, bf, bo, bp, out);
}

// Round 19
// 555.835 us; speedup vs baseline: 1.0569x; 1.0569x over previous
//
#include <hip/hip_runtime.h>

// LSTM, B=128, T=256 (255 steps), H=512, V=128, C=128.  OUTPUT = FLOAT32.
// Round 19: HALVED GROUP FAN-OUT. 8 groups x 16 batch rows; now 16 WGs/group
// x 512 threads (8 waves, 2/SIMD -> TLP). WG w owns h-cols [32w,32w+32).
// Wave v = K-EIGHTH (64 k): A-fragments shared across the WG's two col-halves
// -> group L2 traffic halves (16 consumers x 32KB = 0.5MB/step); each wave
// polls only 2 producer tags (s_load_dwordx2). Protocol = r15's proven one:
// plain data stores/loads via XCD L2 (4-parity buffer), scalar tag poll
// (s_dcache_inv + s_load), WG tag posted by last of 8 waves after vmcnt
// drain, agent-scope B-tags + bounded fallback (no-hang). Poll-set union of
// 8 waves covers all 16 producers -> group skew <=1 step -> parity-safe.

typedef __attribute__((ext_vector_type(8))) short short8;
typedef __attribute__((ext_vector_type(4))) float f32x4;
typedef __attribute__((ext_vector_type(2))) unsigned int u32x2;
typedef __attribute__((ext_vector_type(16))) unsigned int u32x16;

#define NGROUPS 8
#define WPG 16            // workgroups per group
#define HDIM 512
#define TT 256
#define NSTEPS 255
#define CDIM 128
#define PGW 8192          // u32 words per (parity,group): 2 planes x 4096
#define PLANE_W 4096
#define TAGB_OFF 256      // u32 offset of fallback (agent) tag region

__device__ unsigned int g_hbuf[4 * NGROUPS * PGW];              // 1 MB
__device__ unsigned int g_sync[TAGB_OFF + NGROUPS * WPG * 16];  // tags

static __device__ __forceinline__ unsigned short f32_to_bf16(float f) {
  unsigned int u = __builtin_bit_cast(unsigned int, f);
  u += 0x7fffu + ((u >> 16) & 1u);   // RNE
  return (unsigned short)(u >> 16);
}
static __device__ __forceinline__ float bf16_to_f32(unsigned short s) {
  unsigned int u = ((unsigned int)s) << 16;
  return __builtin_bit_cast(float, u);
}
static __device__ __forceinline__ float fast_sigmoid(float v) {
  return __builtin_amdgcn_rcpf(1.0f + __expf(-v));
}
static __device__ __forceinline__ float fast_tanh(float v) {
  return 1.0f - 2.0f * __builtin_amdgcn_rcpf(1.0f + __expf(2.0f * v));
}
static __device__ __forceinline__ const unsigned int* sgpr_ptr(const unsigned int* p) {
  const unsigned long long u = (unsigned long long)p;
  const unsigned int lo = __builtin_amdgcn_readfirstlane((unsigned int)u);
  const unsigned int hi = __builtin_amdgcn_readfirstlane((unsigned int)(u >> 32));
  return (const unsigned int*)(((unsigned long long)hi << 32) | (unsigned long long)lo);
}
static __device__ __forceinline__ unsigned int ag_ld(const unsigned int* p) {
  return __hip_atomic_load(p, __ATOMIC_RELAXED, __HIP_MEMORY_SCOPE_AGENT);
}

// fast poll: K$ invalidate + THIS WAVE'S 2 producer tags from XCD L2
static __device__ __forceinline__ unsigned int poll_min2(const unsigned int* p) {
  u32x2 A;
  asm volatile("s_dcache_inv\n\t"
               "s_load_dwordx2 %0, %1, 0x0\n\t"
               "s_waitcnt lgkmcnt(0)"
               : "=&s"(A) : "s"(p) : "memory");
  return (A[0] < A[1]) ? A[0] : A[1];
}
static __device__ __forceinline__ unsigned int poll_min16(const unsigned int* p) {
  u32x16 A;
  asm volatile("s_dcache_inv\n\t"
               "s_load_dwordx16 %0, %1, 0x0\n\t"
               "s_waitcnt lgkmcnt(0)"
               : "=&s"(A) : "s"(p) : "memory");
  unsigned int m = A[0];
#pragma unroll
  for (int i = 1; i < 16; ++i) m = (A[i] < m) ? A[i] : m;
  return m;
}
static __device__ __forceinline__ void wait_prod2(const unsigned int* tf,
                                                  const unsigned int* fbl,
                                                  unsigned int tgt) {
  for (int spins = 0; spins < 8192; ++spins) {
    if (poll_min2(tf) >= tgt) return;
  }
  for (;;) {  // bounded-risk fallback: proven agent-scope vector poll
    const unsigned int v = ag_ld(fbl);
    if (__all((int)(v >= tgt))) return;
    __builtin_amdgcn_s_sleep(1);
  }
}
static __device__ __forceinline__ void wait_group16(const unsigned int* tagA,
                                                    const unsigned int* fbl,
                                                    unsigned int tgt) {
  for (int spins = 0; spins < 8192; ++spins) {
    if (poll_min16(tagA) >= tgt) return;
  }
  for (;;) {
    const unsigned int v = ag_ld(fbl);
    if (__all((int)(v >= tgt))) return;
    __builtin_amdgcn_s_sleep(1);
  }
}

__global__ __launch_bounds__(512, 2) void lstm_persistent(
    const int* __restrict__ x,
    const float* __restrict__ Wxg, const float* __restrict__ Whg,
    const float* __restrict__ Wxi, const float* __restrict__ Whi,
    const float* __restrict__ Wxf, const float* __restrict__ Whf,
    const float* __restrict__ Wxo, const float* __restrict__ Who,
    const float* __restrict__ Whp,
    const float* __restrict__ bg, const float* __restrict__ bi,
    const float* __restrict__ bf, const float* __restrict__ bo,
    const float* __restrict__ bp,
    float* __restrict__ out)
{
  const int bid = blockIdx.x;
  const int g = bid & 7;
  const int w = bid >> 3;          // 0..15
  const int tid = threadIdx.x;     // 0..511
  const int kq = tid >> 6;         // wave = K-eighth 0..7
  const int lane = tid & 63;
  const int lane15 = lane & 15;
  const int lanehi = lane >> 4;

  __shared__ __align__(16) float part[2][8][16][32][4]; // [pb][kq][row][col][gate] 128KB
  __shared__ unsigned int lds_ctr;

  if (tid == 0) lds_ctr = 0u;

  // ---- one-time: W_h fragments: this wave's 2 k-chunks x 2 col-halves ----
  const float* Whs[4] = {Whg, Whi, Whf, Who};
  short8 wf[2][2][4][2];   // [ch][c][gate][plane] = 128 VGPR
#pragma unroll
  for (int ch = 0; ch < 2; ++ch) {
    const int bcol = (w << 5) + (ch << 4) + lane15;
#pragma unroll
    for (int c = 0; c < 2; ++c) {
      const int ks = (kq << 1) + c;
#pragma unroll
      for (int gate = 0; gate < 4; ++gate) {
        const float* Wh = Whs[gate];
        short8 s0, s1;
#pragma unroll
        for (int e = 0; e < 8; ++e) {
          float v = Wh[(ks * 32 + lanehi * 8 + e) * HDIM + bcol];
          unsigned short a = f32_to_bf16(v);
          unsigned short b = f32_to_bf16(v - bf16_to_f32(a));
          s0[e] = (short)a; s1[e] = (short)b;
        }
        wf[ch][c][gate][0] = s0; wf[ch][c][gate][1] = s1;
      }
    }
  }
  __syncthreads();   // lds_ctr ready

  // ---- elementwise mapping: thread -> (row, col) ----
  const int brow = tid >> 5;          // 0..15
  const int cl = tid & 31;            // 0..31
  const int j = (w << 5) + cl;        // h column 0..511
  const int rowg = g * 16 + brow;
  const float bgv = bg[j], biv = bi[j], bfv = bf[j], bov = bo[j];
  const int woff32 = ((j >> 5) << 8) + ((((j >> 3) & 3) << 4) + brow) * 4 + ((j & 7) >> 1);

  const unsigned int* tagA = sgpr_ptr(g_sync + (g << 4));
  const unsigned int* tf = sgpr_ptr(g_sync + (g << 4) + (kq << 1)); // 2 producers
  unsigned int* myA = g_sync + (g << 4) + w;
  unsigned int* myB = g_sync + TAGB_OFF + ((unsigned)(g * WPG + w) << 4);
  const unsigned int* fbl = g_sync + TAGB_OFF +
      ((unsigned)(g * WPG + (kq << 1) + (lane & 1)) << 4);
  const unsigned int* fblE = g_sync + TAGB_OFF +
      ((unsigned)(g * WPG + (lane & 15)) << 4);

  float creg = 0.0f;

  for (int t = 0; t < NSTEPS; ++t) {
    // x-gather issued early (flies during the poll)
    const int idx = x[rowg * TT + t];
    const float xgv = Wxg[idx * HDIM + j];
    const float xiv = Wxi[idx * HDIM + j];
    const float xfv = Wxf[idx * HDIM + j];
    const float xov = Wxo[idx * HDIM + j];

    f32x4 acc[2][4];   // [ch][gate], 8 independent 6-deep chains
#pragma unroll
    for (int ch = 0; ch < 2; ++ch)
#pragma unroll
      for (int gate = 0; gate < 4; ++gate) acc[ch][gate] = f32x4{0.f,0.f,0.f,0.f};

    if (t > 0) {
      wait_prod2(tf, fbl, (unsigned int)t);
      // data loads: plain, XCD-L2-local; wave's 2 k-chunks x 2 planes
      const char* p0 = (const char*)(g_hbuf +
          ((size_t)((t & 3) * NGROUPS + g)) * PGW) + (kq << 11) + (lane << 4);
      short8 a0[2], a1[2];
#pragma unroll
      for (int c = 0; c < 2; ++c) {
        a0[c] = *(const short8*)(p0 + c * 1024);
        a1[c] = *(const short8*)(p0 + PLANE_W * 4 + c * 1024);
      }
#pragma unroll
      for (int c = 0; c < 2; ++c) {
#pragma unroll
        for (int ch = 0; ch < 2; ++ch) {
#pragma unroll
          for (int gate = 0; gate < 4; ++gate) {
            acc[ch][gate] = __builtin_amdgcn_mfma_f32_16x16x32_bf16(a0[c], wf[ch][c][gate][0], acc[ch][gate], 0, 0, 0);
            acc[ch][gate] = __builtin_amdgcn_mfma_f32_16x16x32_bf16(a0[c], wf[ch][c][gate][1], acc[ch][gate], 0, 0, 0);
            acc[ch][gate] = __builtin_amdgcn_mfma_f32_16x16x32_bf16(a1[c], wf[ch][c][gate][0], acc[ch][gate], 0, 0, 0);
          }
        }
      }
    }
    {
      const int crow = lanehi << 2;   // C/D: row=(lane>>4)*4+r, col=lane&15
      const int pb = t & 1;
#pragma unroll
      for (int ch = 0; ch < 2; ++ch)
#pragma unroll
        for (int r = 0; r < 4; ++r) {
          f32x4 vr;
#pragma unroll
          for (int gate = 0; gate < 4; ++gate) vr[gate] = acc[ch][gate][r];
          *(f32x4*)&part[pb][kq][crow + r][(ch << 4) + lane15][0] = vr;
        }
    }
    __syncthreads();   // the ONE barrier per step

    const int pb = t & 1;
    f32x4 pre = *(const f32x4*)&part[pb][0][brow][cl][0];
#pragma unroll
    for (int q = 1; q < 8; ++q)
      pre += *(const f32x4*)&part[pb][q][brow][cl][0];
    const float pg = pre[0] + xgv + bgv;
    const float pi = pre[1] + xiv + biv;
    const float pf = pre[2] + xfv + bfv;
    const float po = pre[3] + xov + bov;
    const float gv = fast_tanh(pg);
    const float iv = fast_sigmoid(pi);
    const float fv = fast_sigmoid(pf);
    const float ov = fast_sigmoid(po);
    creg = gv * iv + creg * fv;
    const float hv = fast_tanh(creg) * ov;

    const unsigned short h0 = f32_to_bf16(hv);
    const unsigned short h1 = f32_to_bf16(hv - bf16_to_f32(h0));
    const unsigned int pa = (unsigned int)h0 | ((unsigned int)h1 << 16);
    const unsigned int na = (unsigned int)__shfl_xor((int)pa, 1);
    if (!(cl & 1)) {
      unsigned int* dst0 = g_hbuf +
          ((size_t)(((t + 1) & 3) * NGROUPS + g)) * PGW;
      const unsigned int w0 = (pa & 0xffffu) | ((na & 0xffffu) << 16);  // plane0
      const unsigned int w1 = (pa >> 16) | (na & 0xffff0000u);          // plane1
      dst0[woff32] = w0;
      dst0[PLANE_W + woff32] = w1;
    }
    asm volatile("s_waitcnt vmcnt(0)" ::: "memory");  // THIS wave's stores acked
    if (lane == 0) {
      const unsigned int old = atomicAdd(&lds_ctr, 1u);
      if ((old & 7u) == 7u) {   // last of this WG's 8 waves for step t
        __hip_atomic_store(myA, (unsigned int)(t + 1), __ATOMIC_RELAXED,
                           __HIP_MEMORY_SCOPE_WORKGROUP);   // plain -> XCD L2
        __hip_atomic_store(myB, (unsigned int)(t + 1), __ATOMIC_RELAXED,
                           __HIP_MEMORY_SCOPE_AGENT);       // LLC fallback copy
      }
    }
  }

  // ---- epilogue: out = h^255 @ W_hp + b_p ----
  wait_group16(tagA, fblE, (unsigned int)NSTEPS);
  __syncthreads();
  {
    const unsigned int* src =
        g_hbuf + ((size_t)((NSTEPS & 3) * NGROUPS + g)) * PGW;
    const int bq = tid >> 5;          // row 0..15
    const int q31 = tid & 31;
    const int cloc = q31 >> 2;        // 0..7
    const int ksl2 = q31 & 3;         // k-slice of 128
    const int cc = (w << 3) + cloc;   // output col 0..127
    float sum = 0.0f;
    for (int k = ksl2 * 128; k < ksl2 * 128 + 128; k += 2) {
      const int pk = ((k >> 5) << 8) + ((((k >> 3) & 3) << 4) + bq) * 4 + ((k & 7) >> 1);
      const unsigned int w0 = src[pk];
      const unsigned int w1 = src[PLANE_W + pk];
      const float hk0 = bf16_to_f32((unsigned short)(w0 & 0xffffu)) +
                        bf16_to_f32((unsigned short)(w1 & 0xffffu));
      const float hk1 = bf16_to_f32((unsigned short)(w0 >> 16)) +
                        bf16_to_f32((unsigned short)(w1 >> 16));
      sum += hk0 * Whp[k * CDIM + cc] + hk1 * Whp[(k + 1) * CDIM + cc];
    }
    float* gb = &part[0][0][0][0][0];
    gb[tid] = sum;
    __syncthreads();
    if (ksl2 == 0) {
      const float res = gb[tid] + gb[tid + 1] + gb[tid + 2] + gb[tid + 3] + bp[cc];
      out[(g * 16 + bq) * CDIM + cc] = res;
    }
  }
}

extern "C" void kernel_launch(void* const* d_in, const int* in_sizes, int n_in,
                              void* d_out, int out_size, void* d_ws, size_t ws_size,
                              hipStream_t stream) {
  (void)in_sizes; (void)n_in; (void)out_size; (void)d_ws; (void)ws_size;
  const int* x = (const int*)d_in[0];
  const float* Wxg = (const float*)d_in[1];
  const float* Whg = (const float*)d_in[2];
  const float* Wxi = (const float*)d_in[3];
  const float* Whi = (const float*)d_in[4];
  const float* Wxf = (const float*)d_in[5];
  const float* Whf = (const float*)d_in[6];
  const float* Wxo = (const float*)d_in[7];
  const float* Who = (const float*)d_in[8];
  const float* Whp = (const float*)d_in[9];
  const float* bg = (const float*)d_in[10];
  const float* bi = (const float*)d_in[11];
  const float* bf = (const float*)d_in[12];
  const float* bo = (const float*)d_in[13];
  const float* bp = (const float*)d_in[14];
  float* out = (float*)d_out;

  void* sync_dev = nullptr;
  hipGetSymbolAddress(&sync_dev, HIP_SYMBOL(g_sync));
  hipMemsetAsync(sync_dev, 0,
                 sizeof(unsigned int) * (TAGB_OFF + NGROUPS * WPG * 16),
                 stream);

  lstm_persistent<<<dim3(128), dim3(512), 0, stream>>>(
      x, Wxg, Whg, Wxi, Whi, Wxf, Whf, Wxo, Who, Whp,
      bg, bi, bf, bo, bp, out);
}

// Round 20
// 438.470 us; speedup vs baseline: 1.3398x; 1.2677x over previous
//
#include <hip/hip_runtime.h>

// LSTM, B=128, T=256 (255 steps), H=512, V=128, C=128.  OUTPUT = FLOAT32.
// 8 groups x 16 batch rows; 32 WGs/group; WG w owns h-cols [16w,16w+16).
// Wave v (of 4) = K-slice ks in [4v,4v+4) for ALL 4 gates.
// Round 20: ADVISORY TAG + SELF-VALIDATING DATA (r15 wait + r18 validation).
// Producer: single plain 8B store per col-pair (u64 = [h0 pair | h1 pair],
// 2-bit step field in h1 LSBs, atomic per-store); wave 3 posts the WG tag
// immediately -- NO vmcnt drain, NO LDS last-of-4 counter (both were serial
// ~350cyc/step). Consumer: r15's cheap scalar XCD-L2 tag poll (s_dcache_inv
// + s_load_dwordx8 over its 8 producers), then plain 16B loads, bit-check
// each u64; rare mismatch (tag beat a sibling wave's store) -> bounded
// agent-scope re-load. Replay-safe without data memset: stale parity fields
// never match the first steps' expected F (F(s)=((s>>2)+1)&3; 16-step
// ambiguity >> 1-step group skew). Tags (20KB) memset per launch.

typedef __attribute__((ext_vector_type(8))) short short8;
typedef __attribute__((ext_vector_type(4))) float f32x4;
typedef __attribute__((ext_vector_type(4))) unsigned int u32x4;
typedef __attribute__((ext_vector_type(8))) unsigned int u32x8;
typedef __attribute__((ext_vector_type(16))) unsigned int u32x16;

#define NGROUPS 8
#define WGS_PER_GROUP 32
#define HDIM 512
#define TT 256
#define NSTEPS 255
#define CDIM 128
#define PGQ 4096          // u64 words per (parity,group)
#define TAGB_OFF 1024     // u32 offset of fallback (agent) tag region

__device__ unsigned long long g_hbuf[4 * NGROUPS * PGQ];   // 1 MB, 4 parities
__device__ unsigned int g_sync[TAGB_OFF + NGROUPS * WGS_PER_GROUP * 16];

static __device__ __forceinline__ unsigned short f32_to_bf16(float f) {
  unsigned int u = __builtin_bit_cast(unsigned int, f);
  u += 0x7fffu + ((u >> 16) & 1u);   // RNE
  return (unsigned short)(u >> 16);
}
static __device__ __forceinline__ float bf16_to_f32(unsigned short s) {
  unsigned int u = ((unsigned int)s) << 16;
  return __builtin_bit_cast(float, u);
}
static __device__ __forceinline__ float fast_sigmoid(float v) {
  return __builtin_amdgcn_rcpf(1.0f + __expf(-v));
}
static __device__ __forceinline__ float fast_tanh(float v) {
  return 1.0f - 2.0f * __builtin_amdgcn_rcpf(1.0f + __expf(2.0f * v));
}
static __device__ __forceinline__ const unsigned int* sgpr_ptr(const unsigned int* p) {
  const unsigned long long u = (unsigned long long)p;
  const unsigned int lo = __builtin_amdgcn_readfirstlane((unsigned int)u);
  const unsigned int hi = __builtin_amdgcn_readfirstlane((unsigned int)(u >> 32));
  return (const unsigned int*)(((unsigned long long)hi << 32) | (unsigned long long)lo);
}
static __device__ __forceinline__ unsigned int ag_ld(const unsigned int* p) {
  return __hip_atomic_load(p, __ATOMIC_RELAXED, __HIP_MEMORY_SCOPE_AGENT);
}
static __device__ __forceinline__ unsigned long long ag_ld64(const unsigned long long* p) {
  return __hip_atomic_load(p, __ATOMIC_RELAXED, __HIP_MEMORY_SCOPE_AGENT);
}
// step-field bits for data of step s, as a mask on the h1-pair word
static __device__ __forceinline__ unsigned int fbits(int s) {
  const unsigned int F = (unsigned int)(((s >> 2) + 1) & 3);
  return (F & 1u) | ((F >> 1) << 16);
}

static __device__ __forceinline__ unsigned int poll_min8(const unsigned int* p) {
  u32x8 A;
  asm volatile("s_dcache_inv\n\t"
               "s_load_dwordx8 %0, %1, 0x0\n\t"
               "s_waitcnt lgkmcnt(0)"
               : "=&s"(A) : "s"(p) : "memory");
  unsigned int m = A[0];
#pragma unroll
  for (int i = 1; i < 8; ++i) m = (A[i] < m) ? A[i] : m;
  return m;
}
static __device__ __forceinline__ unsigned int poll_min32(const unsigned int* p) {
  u32x16 A, B;
  asm volatile("s_dcache_inv\n\t"
               "s_load_dwordx16 %0, %1, 0x0\n\t"
               "s_waitcnt lgkmcnt(0)"
               : "=&s"(A) : "s"(p) : "memory");
  unsigned int m = A[0];
#pragma unroll
  for (int i = 1; i < 16; ++i) m = (A[i] < m) ? A[i] : m;
  asm volatile("s_load_dwordx16 %0, %1, 0x40\n\t"
               "s_waitcnt lgkmcnt(0)"
               : "=&s"(B) : "s"(p) : "memory");
#pragma unroll
  for (int i = 0; i < 16; ++i) m = (B[i] < m) ? B[i] : m;
  return m;
}
static __device__ __forceinline__ void wait_prod8(const unsigned int* tag8,
                                                  const unsigned int* tagBlane,
                                                  unsigned int tgt) {
  for (int spins = 0; spins < 4096; ++spins) {
    if (poll_min8(tag8) >= tgt) return;
  }
  for (;;) {  // bounded-risk fallback: proven agent-scope vector poll
    const unsigned int v = ag_ld(tagBlane);
    if (__all((int)(v >= tgt))) return;
    __builtin_amdgcn_s_sleep(1);
  }
}
static __device__ __forceinline__ void wait_group32(const unsigned int* tagA,
                                                    const unsigned int* tagBlane,
                                                    unsigned int tgt) {
  for (int spins = 0; spins < 4096; ++spins) {
    if (poll_min32(tagA) >= tgt) return;
  }
  for (;;) {
    const unsigned int v = ag_ld(tagBlane);
    if (__all((int)(v >= tgt))) return;
    __builtin_amdgcn_s_sleep(1);
  }
}

__global__ __launch_bounds__(256, 1) void lstm_persistent(
    const int* __restrict__ x,
    const float* __restrict__ Wxg, const float* __restrict__ Whg,
    const float* __restrict__ Wxi, const float* __restrict__ Whi,
    const float* __restrict__ Wxf, const float* __restrict__ Whf,
    const float* __restrict__ Wxo, const float* __restrict__ Who,
    const float* __restrict__ Whp,
    const float* __restrict__ bg, const float* __restrict__ bi,
    const float* __restrict__ bf, const float* __restrict__ bo,
    const float* __restrict__ bp,
    float* __restrict__ out)
{
  const int bid = blockIdx.x;
  const int g = bid & 7;
  const int w = bid >> 3;
  const int tid = threadIdx.x;
  const int wave = tid >> 6;
  const int lane = tid & 63;
  const int lane15 = lane & 15;
  const int lanehi = lane >> 4;

  __shared__ __align__(16) float part[2][4][16][16][4]; // [pb][wv][row][col][gate]
  __shared__ int lds_x[16][TT];                         // 16KB

  for (int i = tid; i < 16 * TT; i += 256)
    ((int*)lds_x)[i] = x[g * 16 * TT + i];

  // ---- one-time: W_h fragments, 2-plane bf16 split, this wave's 4 k-steps ----
  const float* Whs[4] = {Whg, Whi, Whf, Who};
  const int bcol = (w << 4) + lane15;
  short8 wf[4][4][2];
#pragma unroll
  for (int gate = 0; gate < 4; ++gate) {
    const float* Wh = Whs[gate];
#pragma unroll
    for (int ksl = 0; ksl < 4; ++ksl) {
      const int ksg = (wave << 2) + ksl;
      short8 s0, s1;
#pragma unroll
      for (int e = 0; e < 8; ++e) {
        float v = Wh[(ksg * 32 + lanehi * 8 + e) * HDIM + bcol];
        unsigned short a = f32_to_bf16(v);
        unsigned short b = f32_to_bf16(v - bf16_to_f32(a));
        s0[e] = (short)a; s1[e] = (short)b;
      }
      wf[gate][ksl][0] = s0; wf[gate][ksl][1] = s1;
    }
  }
  __syncthreads();   // lds_x ready

  // ---- elementwise mapping ----
  const int brow = tid >> 4;
  const int jl = tid & 15;
  const int j = (w << 4) + jl;
  const float bgv = bg[j], biv = bi[j], bfv = bf[j], bov = bo[j];
  const int pidx = ((j >> 5) << 8) + ((((j >> 3) & 3) << 4) + brow) * 4 + ((j & 7) >> 1);

  const unsigned int* tagA = sgpr_ptr(g_sync + (g << 5));
  const unsigned int* tag8 = sgpr_ptr(g_sync + (g << 5) + (wave << 3));
  const unsigned int* tagBlane =
      g_sync + TAGB_OFF + ((unsigned)(g * 32 + (lane & 31)) << 4);
  unsigned int* myA = g_sync + (g << 5) + w;
  unsigned int* myB = g_sync + TAGB_OFF + ((unsigned)(g * 32 + w) << 4);

  float creg = 0.0f;

  for (int t = 0; t < NSTEPS; ++t) {
    // x-gather issued early (flies during the poll)
    const int idx = lds_x[brow][t];
    const float xgv = Wxg[idx * HDIM + j];
    const float xiv = Wxi[idx * HDIM + j];
    const float xfv = Wxf[idx * HDIM + j];
    const float xov = Wxo[idx * HDIM + j];

    f32x4 accA[4] = {{0.f,0.f,0.f,0.f},{0.f,0.f,0.f,0.f},
                     {0.f,0.f,0.f,0.f},{0.f,0.f,0.f,0.f}};
    f32x4 accB[4] = {{0.f,0.f,0.f,0.f},{0.f,0.f,0.f,0.f},
                     {0.f,0.f,0.f,0.f},{0.f,0.f,0.f,0.f}};
    if (t > 0) {
      wait_prod8(tag8, tagBlane, (unsigned int)t);   // advisory tag (cheap)
      asm volatile("" ::: "memory");

      const unsigned int expw = fbits(t);
      const unsigned long long* p0q =
          g_hbuf + ((size_t)((t & 3) * NGROUPS + g)) * PGQ;
      u32x4 qa[8];   // [ksl*2 + half]: {w0#0,w1#0,w0#1,w1#1}

      // plain 16B loads (cold L1 -> fresh from XCD L2)
#pragma unroll
      for (int ksl = 0; ksl < 4; ++ksl) {
        const int base = ((wave << 2) + ksl) * 256 + (lane << 2);
        qa[ksl * 2]     = *(const u32x4*)(p0q + base);
        qa[ksl * 2 + 1] = *(const u32x4*)(p0q + base + 2);
      }
      int ok = 1;
#pragma unroll
      for (int i = 0; i < 8; ++i)
        ok &= (((qa[i][1] ^ expw) & 0x00010001u) == 0u) &
              (((qa[i][3] ^ expw) & 0x00010001u) == 0u);

      // rare: tag beat a sibling wave's store -> coherent re-load (bounded)
      unsigned int sweeps = 0;
      while (!__all(ok)) {
#pragma unroll
        for (int ksl = 0; ksl < 4; ++ksl) {
          const int base = ((wave << 2) + ksl) * 256 + (lane << 2);
#pragma unroll
          for (int u = 0; u < 2; ++u) {
            const unsigned long long v0 = ag_ld64(p0q + base + 2 * u);
            const unsigned long long v1 = ag_ld64(p0q + base + 2 * u + 1);
            qa[ksl * 2 + u][0] = (unsigned int)v0;
            qa[ksl * 2 + u][1] = (unsigned int)(v0 >> 32);
            qa[ksl * 2 + u][2] = (unsigned int)v1;
            qa[ksl * 2 + u][3] = (unsigned int)(v1 >> 32);
          }
        }
        ok = 1;
#pragma unroll
        for (int i = 0; i < 8; ++i)
          ok &= (((qa[i][1] ^ expw) & 0x00010001u) == 0u) &
                (((qa[i][3] ^ expw) & 0x00010001u) == 0u);
        if (++sweeps > 65536u) break;   // bug -> wrong answer, not hang
      }

      // unpack planes + 8 independent MFMA chains
#pragma unroll
      for (int ksl = 0; ksl < 4; ++ksl) {
        const u32x4 A = qa[ksl * 2], B = qa[ksl * 2 + 1];
        const short8 a0 = __builtin_bit_cast(short8, (u32x4){A[0], A[2], B[0], B[2]});
        const short8 a1 = __builtin_bit_cast(short8, (u32x4){A[1], A[3], B[1], B[3]});
        if (ksl < 2) {
#pragma unroll
          for (int gate = 0; gate < 4; ++gate) {
            accA[gate] = __builtin_amdgcn_mfma_f32_16x16x32_bf16(a0, wf[gate][ksl][0], accA[gate], 0, 0, 0);
            accA[gate] = __builtin_amdgcn_mfma_f32_16x16x32_bf16(a0, wf[gate][ksl][1], accA[gate], 0, 0, 0);
            accA[gate] = __builtin_amdgcn_mfma_f32_16x16x32_bf16(a1, wf[gate][ksl][0], accA[gate], 0, 0, 0);
          }
        } else {
#pragma unroll
          for (int gate = 0; gate < 4; ++gate) {
            accB[gate] = __builtin_amdgcn_mfma_f32_16x16x32_bf16(a0, wf[gate][ksl][0], accB[gate], 0, 0, 0);
            accB[gate] = __builtin_amdgcn_mfma_f32_16x16x32_bf16(a0, wf[gate][ksl][1], accB[gate], 0, 0, 0);
            accB[gate] = __builtin_amdgcn_mfma_f32_16x16x32_bf16(a1, wf[gate][ksl][0], accB[gate], 0, 0, 0);
          }
        }
      }
    }

    {
      const int crow = lanehi << 2;   // C/D: row=(lane>>4)*4+r, col=lane&15
      const int pb = t & 1;
#pragma unroll
      for (int r = 0; r < 4; ++r) {
        f32x4 vr;
#pragma unroll
        for (int gate = 0; gate < 4; ++gate)
          vr[gate] = accA[gate][r] + accB[gate][r];
        *(f32x4*)&part[pb][wave][crow + r][lane15][0] = vr;   // ds_write_b128
      }
    }
    __syncthreads();   // the ONE barrier per step

    const int pb = t & 1;
    const f32x4 s0 = *(const f32x4*)&part[pb][0][brow][jl][0];
    const f32x4 s1 = *(const f32x4*)&part[pb][1][brow][jl][0];
    const f32x4 s2 = *(const f32x4*)&part[pb][2][brow][jl][0];
    const f32x4 s3 = *(const f32x4*)&part[pb][3][brow][jl][0];
    const f32x4 pre = s0 + s1 + s2 + s3;
    const float pg = pre[0] + xgv + bgv;
    const float pi = pre[1] + xiv + biv;
    const float pf = pre[2] + xfv + bfv;
    const float po = pre[3] + xov + bov;
    const float gv = fast_tanh(pg);
    const float iv = fast_sigmoid(pi);
    const float fv = fast_sigmoid(pf);
    const float ov = fast_sigmoid(po);
    creg = gv * iv + creg * fv;
    const float hv = fast_tanh(creg) * ov;

    // pack u64 [h0 pair | h1 pair], embed step field in h1 LSBs; plain store
    const unsigned short h0 = f32_to_bf16(hv);
    const unsigned short h1 = f32_to_bf16(hv - bf16_to_f32(h0));
    const unsigned int pa = (unsigned int)h0 | ((unsigned int)h1 << 16);
    const unsigned int na = (unsigned int)__shfl_xor((int)pa, 1);
    if (!(jl & 1)) {
      unsigned long long* dstq =
          g_hbuf + ((size_t)(((t + 1) & 3) * NGROUPS + g)) * PGQ;
      const unsigned int w0 = (pa & 0xffffu) | ((na & 0xffffu) << 16);   // h0 pair
      unsigned int w1 = (pa >> 16) | (na & 0xffff0000u);                 // h1 pair
      w1 = (w1 & ~0x00010001u) | fbits(t + 1);
      dstq[pidx] = (unsigned long long)w0 | ((unsigned long long)w1 << 32);
    }
    // advisory tag: wave 3 posts right after its own store issue -- NO drain
    if (wave == 3 && lane == 0) {
      __hip_atomic_store(myA, (unsigned int)(t + 1), __ATOMIC_RELAXED,
                         __HIP_MEMORY_SCOPE_WORKGROUP);   // plain -> XCD L2
      __hip_atomic_store(myB, (unsigned int)(t + 1), __ATOMIC_RELAXED,
                         __HIP_MEMORY_SCOPE_AGENT);       // LLC fallback copy
    }
  }

  // ---- epilogue: out = h^255 @ W_hp + b_p ----
  wait_group32(tagA, tagBlane, (unsigned int)NSTEPS);
  __syncthreads();
  {
    const unsigned long long* srcq =
        g_hbuf + ((size_t)((NSTEPS & 3) * NGROUPS + g)) * PGQ;
    const int bq = tid >> 4;
    const int q15 = tid & 15;
    const int cloc = q15 >> 2;
    const int ksl2 = q15 & 3;
    const int cc = (w << 2) + cloc;
    const unsigned int expw = fbits(NSTEPS);
    float sum = 0.0f;
    for (int k = ksl2 * 128; k < ksl2 * 128 + 128; k += 2) {
      const int pk = ((k >> 5) << 8) + ((((k >> 3) & 3) << 4) + bq) * 4 + ((k & 7) >> 1);
      unsigned long long qv = srcq[pk];
      if ((((unsigned int)(qv >> 32) ^ expw) & 0x00010001u) != 0u) {
        unsigned int tries = 0;
        do {
          __builtin_amdgcn_s_sleep(1);
          qv = ag_ld64(srcq + pk);
        } while ((((unsigned int)(qv >> 32) ^ expw) & 0x00010001u) != 0u &&
                 ++tries < 65536u);
      }
      const unsigned int w0 = (unsigned int)qv;
      const unsigned int w1 = (unsigned int)(qv >> 32);
      const float hk0 = bf16_to_f32((unsigned short)(w0 & 0xffffu)) +
                        bf16_to_f32((unsigned short)(w1 & 0xffffu));
      const float hk1 = bf16_to_f32((unsigned short)(w0 >> 16)) +
                        bf16_to_f32((unsigned short)(w1 >> 16));
      sum += hk0 * Whp[k * CDIM + cc] + hk1 * Whp[(k + 1) * CDIM + cc];
    }
    float* gb = &part[0][0][0][0][0];
    gb[tid] = sum;
    __syncthreads();
    if (ksl2 == 0) {
      const float res = gb[tid] + gb[tid + 1] + gb[tid + 2] + gb[tid + 3] + bp[cc];
      out[(g * 16 + bq) * CDIM + cc] = res;
    }
  }
}

extern "C" void kernel_launch(void* const* d_in, const int* in_sizes, int n_in,
                              void* d_out, int out_size, void* d_ws, size_t ws_size,
                              hipStream_t stream) {
  (void)in_sizes; (void)n_in; (void)out_size; (void)d_ws; (void)ws_size;
  const int* x = (const int*)d_in[0];
  const float* Wxg = (const float*)d_in[1];
  const float* Whg = (const float*)d_in[2];
  const float* Wxi = (const float*)d_in[3];
  const float* Whi = (const float*)d_in[4];
  const float* Wxf = (const float*)d_in[5];
  const float* Whf = (const float*)d_in[6];
  const float* Wxo = (const float*)d_in[7];
  const float* Who = (const float*)d_in[8];
  const float* Whp = (const float*)d_in[9];
  const float* bg = (const float*)d_in[10];
  const float* bi = (const float*)d_in[11];
  const float* bf = (const float*)d_in[12];
  const float* bo = (const float*)d_in[13];
  const float* bp = (const float*)d_in[14];
  float* out = (float*)d_out;

  // tags must reset each launch (monotone counters); data buffer needs no
  // reset -- stale step-fields never match the first steps' expected F.
  void* sync_dev = nullptr;
  hipGetSymbolAddress(&sync_dev, HIP_SYMBOL(g_sync));
  hipMemsetAsync(sync_dev, 0,
                 sizeof(unsigned int) * (TAGB_OFF + NGROUPS * WGS_PER_GROUP * 16),
                 stream);

  lstm_persistent<<<dim3(256), dim3(256), 0, stream>>>(
      x, Wxg, Whg, Wxi, Whi, Wxf, Whf, Wxo, Who, Whp,
      bg, bi, bf, bo, bp, out);
}